// Round 19
// baseline (213.695 us; speedup 1.0000x reference)
//
#include <hip/hip_runtime.h>

#define C_DIM  384
#define HEADS  6
#define HD     64
#define FF_DIM 1536
#define LN_EPS 1e-3f
#define TSEQ   2048
#define BATCH  4
#define LOG2E  1.4426950408889634f
#define QK_SCALE 0.18033688011112042f   // 0.125 * log2(e), folded into Q

typedef __attribute__((ext_vector_type(2))) float          f32x2;
typedef __attribute__((ext_vector_type(4))) float          f32x4;
typedef __attribute__((ext_vector_type(4))) float          float4_t;
typedef __attribute__((ext_vector_type(8))) short          bfrag;     // 8 bf16
typedef __attribute__((ext_vector_type(4))) unsigned short ushort4_t;
typedef __attribute__((ext_vector_type(8))) unsigned short ushort8_t;

__device__ inline unsigned short f2bf(float f) {
    unsigned int u = __builtin_bit_cast(unsigned int, f);
    u += 0x7fff + ((u >> 16) & 1);          // RNE
    return (unsigned short)(u >> 16);
}
// truncating convert — P matrix only (values in [0,1], re-normalized)
__device__ inline unsigned short f2bf_t(float f) {
    return (unsigned short)(__builtin_bit_cast(unsigned int, f) >> 16);
}
__device__ inline float bf2f(unsigned short u) {
    return __builtin_bit_cast(float, (unsigned int)u << 16);
}

// async global->LDS, 16 B per lane. LDS dest is wave-uniform base + lane*16.
__device__ inline void gload_lds16(const void* g, void* l) {
    __builtin_amdgcn_global_load_lds(
        (const __attribute__((address_space(1))) unsigned int*)g,
        (__attribute__((address_space(3))) unsigned int*)l,
        16, 0, 0);
}

// chunked XCD swizzle: HW maps flat blockIdx round-robin (bid&7 = XCD, r10).
__device__ inline int xcd_chunk(int flat, int nwg) {
    return (flat >> 3) + (flat & 7) * (nwg >> 3);
}

// ---------------------------------------------------------------------------
// Fused: all weight transposes (W[K][N] f32 -> Wt[N][K] bf16) + x -> bf16.
// ---------------------------------------------------------------------------
__global__ __launch_bounds__(256)
void prep_all(const float* __restrict__ Wq, const float* __restrict__ Wk,
              const float* __restrict__ Wv, const float* __restrict__ Wo,
              const float* __restrict__ W1, const float* __restrict__ W2,
              const float* __restrict__ x,
              unsigned short* __restrict__ Dqkv, unsigned short* __restrict__ Do_,
              unsigned short* __restrict__ D1, unsigned short* __restrict__ D2,
              unsigned short* __restrict__ xb)
{
    __shared__ float tile[32][33];
    const int bidx = blockIdx.x;
    const int tx = threadIdx.x, ty = threadIdx.y;
    if (bidx >= 1728) {
        const int i = (bidx - 1728) * 256 + ty * 32 + tx;
        float4_t v = ((const float4_t*)x)[i];
        ushort4_t o = { f2bf(v.x), f2bf(v.y), f2bf(v.z), f2bf(v.w) };
        ((ushort4_t*)xb)[i] = o;
        return;
    }
    const float* W; unsigned short* D;
    int K, N, nx, ny;
    if (bidx < 576) {
        const int z = bidx / 144, r = bidx % 144;
        W = z == 0 ? Wq : (z == 1 ? Wk : (z == 2 ? Wv : Wo));
        D = z == 3 ? Do_ : Dqkv + (size_t)z * C_DIM * C_DIM;
        K = N = C_DIM; nx = r % 12; ny = r / 12;
    } else if (bidx < 1152) {
        const int r = bidx - 576;
        W = W1; D = D1; K = C_DIM; N = FF_DIM; nx = r % 48; ny = r / 48;
    } else {
        const int r = bidx - 1152;
        W = W2; D = D2; K = FF_DIM; N = C_DIM; nx = r % 12; ny = r / 12;
    }
    const int n0 = nx * 32, k0 = ny * 32;
    #pragma unroll
    for (int i = 0; i < 32; i += 8)
        tile[ty + i][tx] = W[(size_t)(k0 + ty + i) * N + n0 + tx];
    __syncthreads();
    #pragma unroll
    for (int i = 0; i < 32; i += 8)
        D[(size_t)(n0 + ty + i) * K + k0 + tx] = f2bf(tile[tx][ty + i]);
}

// ---------------------------------------------------------------------------
// V transpose only: qkv v-cols -> vt[bh][d][t] bf16.
// ---------------------------------------------------------------------------
__global__ __launch_bounds__(256)
void vtrans_kernel(const unsigned short* __restrict__ qkv,
                   unsigned short* __restrict__ vt)
{
    __shared__ unsigned short tile[32][34];
    const int tx = threadIdx.x, ty = threadIdx.y;
    const int bh = blockIdx.z, b = bh / HEADS, h = bh % HEADS;
    const int t0 = blockIdx.x * 32, d0 = blockIdx.y * 32;
    #pragma unroll
    for (int i = 0; i < 32; i += 8)
        tile[ty + i][tx] = qkv[(size_t)(b * TSEQ + t0 + ty + i) * 1152 + 2 * C_DIM + h * HD + d0 + tx];
    __syncthreads();
    #pragma unroll
    for (int i = 0; i < 32; i += 8)
        vt[((size_t)bh * HD + d0 + ty + i) * TSEQ + t0 + tx] = tile[tx][ty + i];
}

// ---------------------------------------------------------------------------
// LDS-staged bf16 MFMA GEMM, BM=128 x BN=128 (m97 structure).
// ---------------------------------------------------------------------------
template<int OBF16, int BIAS, int RELU, int QSCALE, int KSPLIT>
__global__ __launch_bounds__(256)
void gemm_lds(const unsigned short* __restrict__ A, const unsigned short* __restrict__ Bt,
              const float* __restrict__ bias, void* __restrict__ Cv,
              unsigned short* __restrict__ ktc,
              int M, int N, int K)
{
    __shared__ __align__(16) unsigned short As[16 * 512];   // 16 frags x 1KB
    __shared__ __align__(16) unsigned short Bs[16 * 512];

    const int t = threadIdx.x, lane = t & 63, w = t >> 6;
    const int ln16 = lane & 15, hi16 = lane >> 4;
    const int wr = w >> 1, wc = w & 1;
    const int nwg = gridDim.x * gridDim.y;
    const int L = xcd_chunk(blockIdx.y * gridDim.x + blockIdx.x, nwg);
    const int row0 = (L / gridDim.x) * 128, col0 = (L % gridDim.x) * 128;

    f32x4 acc[4][4] = {};

    for (int k0 = 0; k0 < K; k0 += 64) {
        #pragma unroll
        for (int i = 0; i < 4; ++i) {
            const int f  = w * 4 + i;
            const int ks = f >> 3, rf = f & 7;
            const int row = rf * 16 + ln16;
            const int kc  = k0 + ks * 32 + hi16 * 8;
            gload_lds16(&A [(size_t)(row0 + row) * K + kc], &As[f * 512]);
            gload_lds16(&Bt[(size_t)(col0 + row) * K + kc], &Bs[f * 512]);
        }
        __syncthreads();
        #pragma unroll
        for (int ks = 0; ks < 2; ++ks) {
            bfrag a[4], b[4];
            #pragma unroll
            for (int i = 0; i < 4; ++i)
                a[i] = *(const bfrag*)&As[(ks * 8 + wr * 4 + i) * 512 + lane * 8];
            #pragma unroll
            for (int j = 0; j < 4; ++j)
                b[j] = *(const bfrag*)&Bs[(ks * 8 + wc * 4 + j) * 512 + lane * 8];
            #pragma unroll
            for (int i = 0; i < 4; ++i)
                #pragma unroll
                for (int j = 0; j < 4; ++j)
                    acc[i][j] = __builtin_amdgcn_mfma_f32_16x16x32_bf16(a[i], b[j], acc[i][j], 0, 0, 0);
        }
        __syncthreads();
    }

    #pragma unroll
    for (int j = 0; j < 4; ++j) {
        const int cbase = col0 + wc * 64 + j * 16;      // 16-aligned, head-uniform
        const int col = cbase + ln16;
        const float bv = BIAS ? bias[col] : 0.0f;
        const float sc = (QSCALE && col < C_DIM) ? QK_SCALE : 1.0f;
        const bool kdest = KSPLIT && (cbase >= C_DIM) && (cbase < 2 * C_DIM);
        #pragma unroll
        for (int i = 0; i < 4; ++i) {
            #pragma unroll
            for (int e = 0; e < 4; ++e) {
                const int row = row0 + wr * 64 + i * 16 + hi16 * 4 + e;
                float v = acc[i][j][e] + bv;
                if (RELU) v = fmaxf(v, 0.0f);
                if (QSCALE) v *= sc;
                if (kdest) {
                    const int b  = row >> 11, tt = row & 2047;
                    const int hd = col - C_DIM;                 // h*64 + d
                    const int bh = b * HEADS + (hd >> 6);
                    ktc[((size_t)bh * TSEQ + tt) * HD + (hd & 63)] = f2bf(v);
                } else if (OBF16) {
                    ((unsigned short*)Cv)[(size_t)row * N + col] = f2bf(v);
                } else {
                    ((float*)Cv)[(size_t)row * N + col] = v;
                }
            }
        }
    }
}

// ---------------------------------------------------------------------------
// LDS-staged bf16 MFMA GEMM, BM=64 x BN=128, double-buffered (r18).
// ---------------------------------------------------------------------------
template<int OBF16, int BIAS, int RELU>
__global__ __launch_bounds__(256)
void gemm_lds64(const unsigned short* __restrict__ A, const unsigned short* __restrict__ Bt,
                const float* __restrict__ bias, void* __restrict__ Cv,
                int M, int N, int K)
{
    __shared__ __align__(16) unsigned short As[2][8 * 512];    // 2 x 8 frags
    __shared__ __align__(16) unsigned short Bs[2][16 * 512];   // 2 x 16 frags

    const int t = threadIdx.x, lane = t & 63, w = t >> 6;
    const int ln16 = lane & 15, hi16 = lane >> 4;
    const int wr = w >> 1, wc = w & 1;
    const int nwg = gridDim.x * gridDim.y;
    const int L = xcd_chunk(blockIdx.y * gridDim.x + blockIdx.x, nwg);
    const int row0 = (L / gridDim.x) * 64, col0 = (L % gridDim.x) * 128;

    f32x4 acc[2][4] = {};

    auto stage = [&](int bf, int k0) {
        #pragma unroll
        for (int i = 0; i < 2; ++i) {
            const int f  = w * 2 + i;
            const int ks = f >> 2, rf = f & 3;
            gload_lds16(&A[(size_t)(row0 + rf * 16 + ln16) * K + k0 + ks * 32 + hi16 * 8],
                        &As[bf][f * 512]);
        }
        #pragma unroll
        for (int i = 0; i < 4; ++i) {
            const int f  = w * 4 + i;
            const int ks = f >> 3, cf = f & 7;
            gload_lds16(&Bt[(size_t)(col0 + cf * 16 + ln16) * K + k0 + ks * 32 + hi16 * 8],
                        &Bs[bf][f * 512]);
        }
    };

    int buf = 0;
    stage(0, 0);
    __syncthreads();                       // buf0 staged

    for (int k0 = 0; k0 < K; k0 += 64) {
        if (k0 + 64 < K) stage(buf ^ 1, k0 + 64);   // async, in flight over compute
        #pragma unroll
        for (int ks = 0; ks < 2; ++ks) {
            bfrag a[2], b[4];
            #pragma unroll
            for (int i = 0; i < 2; ++i)
                a[i] = *(const bfrag*)&As[buf][(ks * 4 + wr * 2 + i) * 512 + lane * 8];
            #pragma unroll
            for (int j = 0; j < 4; ++j)
                b[j] = *(const bfrag*)&Bs[buf][(ks * 8 + wc * 4 + j) * 512 + lane * 8];
            #pragma unroll
            for (int i = 0; i < 2; ++i)
                #pragma unroll
                for (int j = 0; j < 4; ++j)
                    acc[i][j] = __builtin_amdgcn_mfma_f32_16x16x32_bf16(a[i], b[j], acc[i][j], 0, 0, 0);
        }
        __syncthreads();                   // drains staging vmcnt + guards reuse
        buf ^= 1;
    }

    #pragma unroll
    for (int j = 0; j < 4; ++j) {
        const int col = col0 + wc * 64 + j * 16 + ln16;
        const float bv = BIAS ? bias[col] : 0.0f;
        #pragma unroll
        for (int i = 0; i < 2; ++i) {
            #pragma unroll
            for (int e = 0; e < 4; ++e) {
                const int row = row0 + wr * 32 + i * 16 + hi16 * 4 + e;
                float v = acc[i][j][e] + bv;
                if (RELU) v = fmaxf(v, 0.0f);
                if (OBF16) ((unsigned short*)Cv)[(size_t)row * N + col] = f2bf(v);
                else       ((float*)Cv)[(size_t)row * N + col] = v;
            }
        }
    }
}

// ---------------------------------------------------------------------------
// attention helpers (s_setprio(1) around MFMA clusters — T5)
// ---------------------------------------------------------------------------
__device__ inline void qk16(const bfrag (&qf)[2][2], const bfrag (&kf)[4][2],
                            f32x4 (&sf)[2][4])
{
    __builtin_amdgcn_s_setprio(1);
    #pragma unroll
    for (int jt = 0; jt < 4; ++jt)
        #pragma unroll
        for (int ks = 0; ks < 2; ++ks) {
            sf[0][jt] = __builtin_amdgcn_mfma_f32_16x16x32_bf16(qf[0][ks], kf[jt][ks], sf[0][jt], 0, 0, 0);
            sf[1][jt] = __builtin_amdgcn_mfma_f32_16x16x32_bf16(qf[1][ks], kf[jt][ks], sf[1][jt], 0, 0, 0);
        }
    __builtin_amdgcn_s_setprio(0);
}

// softmax + PV. Mask applied on the fly.
__device__ inline void softmax_pv(f32x4 (&sf)[2][4], const bfrag (&vf)[4][2],
                                  f32x4 (&acc)[2][4],
                                  float (&mrow)[2][4], float (&lrow)[2][4],
                                  unsigned short (*Ps)[72],
                                  int tok0, int kt, bool last, int ln16, int hi16)
{
    float lmax[2][4];
    bool need = false;
    #pragma unroll
    for (int rf = 0; rf < 2; ++rf)
        #pragma unroll
        for (int e = 0; e < 4; ++e) {
            const int row = tok0 + rf * 16 + hi16 * 4 + e;
            float mx = -1e30f;
            #pragma unroll
            for (int jt = 0; jt < 4; ++jt) {
                float sv = sf[rf][jt][e];
                if (last && (kt * 64 + jt * 16 + ln16 > row)) sv = -1e30f;
                mx = fmaxf(mx, sv);
            }
            lmax[rf][e] = mx;
            need = need || (mx > mrow[rf][e] + 8.0f);
        }
    if (__any(need)) {
        #pragma unroll
        for (int rf = 0; rf < 2; ++rf)
            #pragma unroll
            for (int e = 0; e < 4; ++e) {
                float rm = lmax[rf][e];
                rm = fmaxf(rm, __shfl_xor(rm, 1));
                rm = fmaxf(rm, __shfl_xor(rm, 2));
                rm = fmaxf(rm, __shfl_xor(rm, 4));
                rm = fmaxf(rm, __shfl_xor(rm, 8));
                const float mn = fmaxf(mrow[rf][e], rm);
                const float corr = exp2f(mrow[rf][e] - mn);
                mrow[rf][e] = mn;
                lrow[rf][e] *= corr;
                #pragma unroll
                for (int dt = 0; dt < 4; ++dt) acc[rf][dt][e] *= corr;
            }
    }

    #pragma unroll
    for (int rf = 0; rf < 2; ++rf)
        #pragma unroll
        for (int jt = 0; jt < 4; ++jt)
            #pragma unroll
            for (int e = 0; e < 4; ++e) {
                const int row = tok0 + rf * 16 + hi16 * 4 + e;
                float sv = sf[rf][jt][e];
                if (last && (kt * 64 + jt * 16 + ln16 > row)) sv = -1e30f;
                const float pe = exp2f(sv - mrow[rf][e]);
                lrow[rf][e] += pe;
                Ps[rf * 16 + hi16 * 4 + e][jt * 16 + ln16] = f2bf_t(pe);
            }

    bfrag pf[2][2];
    #pragma unroll
    for (int rf = 0; rf < 2; ++rf)
        #pragma unroll
        for (int ks = 0; ks < 2; ++ks)
            pf[rf][ks] = *(const bfrag*)&Ps[rf * 16 + ln16][ks * 32 + hi16 * 8];
    __builtin_amdgcn_s_setprio(1);
    #pragma unroll
    for (int ks = 0; ks < 2; ++ks)
        #pragma unroll
        for (int rf = 0; rf < 2; ++rf)
            #pragma unroll
            for (int dt = 0; dt < 4; ++dt)
                acc[rf][dt] = __builtin_amdgcn_mfma_f32_16x16x32_bf16(pf[rf][ks], vf[dt][ks], acc[rf][dt], 0, 0, 0);
    __builtin_amdgcn_s_setprio(0);
}

// ---------------------------------------------------------------------------
// 8-wave shared-KV flash attention (guide §B shape). Block = (bh, qt):
// 8 waves x 32-row strips covering rows [qt*256, qt*256+256); all waves share
// the SAME K/V tile stream, LDS double-buffered, staged by all 512 threads
// via gload_lds (1 instr per array per tile per thread). Per-wave causal
// bound NTw predicates compute inside a block-uniform NTmax loop (barriers
// uniform). XOR-chunk swizzle both-sides (r13-verified). Direct normalized
// stores (no partials/combine). 192 blocks, all co-resident; heavy qt first;
// bid&7 XCD swizzle (round-robin confirmed r10).
// ---------------------------------------------------------------------------
__global__ __launch_bounds__(512)
void attn8_kernel(const unsigned short* __restrict__ qkv,
                  const unsigned short* __restrict__ ktc,
                  const unsigned short* __restrict__ vt,
                  unsigned short* __restrict__ att)
{
    __shared__ __align__(16) unsigned short Klds[2][4096];   // 2 x 8KB
    __shared__ __align__(16) unsigned short Vlds[2][4096];
    __shared__ __align__(16) unsigned short Ps[8][32][72];   // per-wave strip

    const int tid  = threadIdx.x;
    const int lane = tid & 63, wid = tid >> 6;
    const int ln16 = lane & 15, hi16 = lane >> 4;
    const int bid = blockIdx.x;            // 0..191
    const int xcd = bid & 7;
    const int i   = bid >> 3;              // 0..23
    const int bh  = xcd * 3 + (i % 3);     // 3 bh per XCD
    const int qt  = 7 - (i / 3);           // heavy blocks first
    const int s   = qt * 8 + wid;          // strip index 0..63
    const int tok0 = s * 32;
    const int NTw   = (s >> 1) + 1;        // this wave's causal tile count
    const int NTmax = qt * 4 + 4;          // block-uniform loop bound
    const int b = bh / HEADS, h = bh % HEADS;
    const size_t qrow0 = (size_t)b * TSEQ;

    // Q fragments (registers, once)
    bfrag qf[2][2];
    #pragma unroll
    for (int rf = 0; rf < 2; ++rf)
        #pragma unroll
        for (int ks = 0; ks < 2; ++ks)
            qf[rf][ks] = *(const bfrag*)&qkv[(qrow0 + tok0 + rf * 16 + ln16) * 1152 + h * HD + ks * 32 + hi16 * 8];

    f32x4 acc[2][4] = {};
    float mrow[2][4], lrow[2][4];
    #pragma unroll
    for (int rf = 0; rf < 2; ++rf)
        #pragma unroll
        for (int e = 0; e < 4; ++e) { mrow[rf][e] = -1e30f; lrow[rf][e] = 0.0f; }

    const unsigned short* Kb = ktc + (size_t)bh * TSEQ * HD;
    const unsigned short* Vb = vt  + (size_t)bh * HD * TSEQ;

    // loop-invariant swizzled LDS byte offsets for fragment reads:
    // logical (row, byte cb) lives at byte row*128 + (cb ^ ((row&7)<<4))
    int off[4][2];
    #pragma unroll
    for (int jt = 0; jt < 4; ++jt)
        #pragma unroll
        for (int ks = 0; ks < 2; ++ks) {
            const int row = jt * 16 + ln16;
            off[jt][ks] = row * 128 + ((ks * 64 + hi16 * 16) ^ ((row & 7) << 4));
        }

    // stage one K+V tile pair into buffer bf: each of 512 threads issues one
    // 16B gload per array. Dest chunk c16 = tid; row r = c16>>3; source chunk
    // inverse-swizzled s16 = (c16&7) ^ (r&7).  (r13-verified scheme)
    auto stage = [&](int bf, int kt) {
        const int r   = tid >> 3;
        const int s16 = (tid & 7) ^ (r & 7);
        gload_lds16(&Kb[(size_t)(kt * 64 + r) * HD + s16 * 8], &Klds[bf][wid * 512]);
        gload_lds16(&Vb[(size_t)r * TSEQ + kt * 64 + s16 * 8], &Vlds[bf][wid * 512]);
    };

    int buf = 0;
    stage(0, 0);
    __syncthreads();                       // buf0 ready

    for (int kt = 0; kt < NTmax; ++kt) {
        if (kt + 1 < NTmax) stage(buf ^ 1, kt + 1);   // async over compute

        if (kt < NTw) {
            const char* Kb8 = (const char*)&Klds[buf][0];
            const char* Vb8 = (const char*)&Vlds[buf][0];
            bfrag kf[4][2], vf[4][2];
            #pragma unroll
            for (int jt = 0; jt < 4; ++jt)
                #pragma unroll
                for (int ks = 0; ks < 2; ++ks) {
                    kf[jt][ks] = *(const bfrag*)(Kb8 + off[jt][ks]);
                    vf[jt][ks] = *(const bfrag*)(Vb8 + off[jt][ks]);
                }

            f32x4 sf[2][4] = {};
            qk16(qf, kf, sf);
            softmax_pv(sf, vf, acc, mrow, lrow, Ps[wid], tok0, kt, kt == NTw - 1, ln16, hi16);
        }

        __syncthreads();                   // drains staging vmcnt + guards reuse
        buf ^= 1;
    }

    // epilogue: reduce l across the 16-lane groups, normalize, store
    #pragma unroll
    for (int rf = 0; rf < 2; ++rf)
        #pragma unroll
        for (int e = 0; e < 4; ++e) {
            float l = lrow[rf][e];
            l += __shfl_xor(l, 1);
            l += __shfl_xor(l, 2);
            l += __shfl_xor(l, 4);
            l += __shfl_xor(l, 8);
            const float inv = 1.0f / l;
            const size_t row = qrow0 + tok0 + rf * 16 + hi16 * 4 + e;
            #pragma unroll
            for (int dt = 0; dt < 4; ++dt)
                att[row * C_DIM + h * HD + dt * 16 + ln16] = f2bf(acc[rf][dt][e] * inv);
        }
}

// ---------------------------------------------------------------------------
// Fused residual add + LayerNorm, vectorized (f32x2 / packed-u32 paths).
// ---------------------------------------------------------------------------
template<int ABF16, int WF32, int WBF>
__global__ __launch_bounds__(256)
void ln_residual_kernel(const void* __restrict__ Av, const float* __restrict__ R,
                        const float* __restrict__ gamma, const float* __restrict__ beta,
                        float* __restrict__ out, unsigned short* __restrict__ outb, int Mrows)
{
    const int lane = threadIdx.x & 63;
    const int wv   = threadIdx.x >> 6;
    const int row  = blockIdx.x * 4 + wv;
    if (row >= Mrows) return;
    const size_t off = (size_t)row * C_DIM;

    float v[6];
    float sum = 0.0f;
    #pragma unroll
    for (int j = 0; j < 3; ++j) {
        const int c = lane * 2 + 128 * j;
        float a0, a1;
        if (ABF16) {
            const unsigned int u = *(const unsigned int*)&((const unsigned short*)Av)[off + c];
            a0 = bf2f((unsigned short)(u & 0xffff));
            a1 = bf2f((unsigned short)(u >> 16));
        } else {
            f32x2 a = *(const f32x2*)&((const float*)Av)[off + c];
            a0 = a.x; a1 = a.y;
        }
        f32x2 r = *(const f32x2*)&R[off + c];
        v[2 * j]     = a0 + r.x;
        v[2 * j + 1] = a1 + r.y;
        sum += v[2 * j] + v[2 * j + 1];
    }
    #pragma unroll
    for (int o = 1; o < 64; o <<= 1) sum += __shfl_xor(sum, o);
    const float mu = sum * (1.0f / C_DIM);

    float sq = 0.0f;
    #pragma unroll
    for (int j = 0; j < 6; ++j) { const float d = v[j] - mu; sq = fmaf(d, d, sq); }
    #pragma unroll
    for (int o = 1; o < 64; o <<= 1) sq += __shfl_xor(sq, o);
    const float rstd = rsqrtf(sq * (1.0f / C_DIM) + LN_EPS);

    #pragma unroll
    for (int j = 0; j < 3; ++j) {
        const int c = lane * 2 + 128 * j;
        f32x2 g  = *(const f32x2*)&gamma[c];
        f32x2 be = *(const f32x2*)&beta[c];
        const float r0 = (v[2 * j]     - mu) * rstd * g.x + be.x;
        const float r1 = (v[2 * j + 1] - mu) * rstd * g.y + be.y;
        if (WF32) { f32x2 o = { r0, r1 }; *(f32x2*)&out[off + c] = o; }
        if (WBF) {
            const unsigned int o = (unsigned int)f2bf(r0) | ((unsigned int)f2bf(r1) << 16);
            *(unsigned int*)&outb[off + c] = o;
        }
    }
}

// ---------------------------------------------------------------------------
extern "C" void kernel_launch(void* const* d_in, const int* in_sizes, int n_in,
                              void* d_out, int out_size, void* d_ws, size_t ws_size,
                              hipStream_t stream)
{
    const float* x   = (const float*)d_in[0];
    const float* Wq  = (const float*)d_in[1];
    const float* Wk  = (const float*)d_in[2];
    const float* Wv  = (const float*)d_in[3];
    const float* Wo  = (const float*)d_in[4];
    const float* bo  = (const float*)d_in[5];
    const float* W1  = (const float*)d_in[6];
    const float* b1  = (const float*)d_in[7];
    const float* W2  = (const float*)d_in[8];
    const float* b2  = (const float*)d_in[9];
    const float* g1  = (const float*)d_in[10];
    const float* be1 = (const float*)d_in[11];
    const float* g2  = (const float*)d_in[12];
    const float* be2 = (const float*)d_in[13];
    float* out = (float*)d_out;

    const int M = BATCH * TSEQ;                  // 8192
    const size_t MC = (size_t)M * C_DIM;

    // ---- workspace layout (bytes) ----
    char* ws = (char*)d_ws;
    unsigned short* qkv = (unsigned short*)ws;                       // M*1152*2 = 18.87 MB
    unsigned short* vt  = (unsigned short*)(ws + (size_t)M*1152*2);  // 6.29 MB
    unsigned short* att = (unsigned short*)(ws + (size_t)M*1152*2 + (size_t)BATCH*HEADS*HD*TSEQ*2); // 6.29 MB
    unsigned short* h1  = (unsigned short*)ws;                       // M*1536*2, aliases qkv+vt
    char* p2 = ws + (size_t)M*1152*2 + (size_t)BATCH*HEADS*HD*TSEQ*2 + MC*2;   // 31.46 MB mark
    unsigned short* xb  = (unsigned short*)p2;                       // MC bf16 (QKV gemm input)
    float* y   = (float*)(p2 + MC*2);                                // MC f32
    unsigned short* ktc = (unsigned short*)(p2 + MC*2 + MC*4);       // 6.29 MB
    unsigned short* x1b = (unsigned short*)(p2 + MC*2 + 2*MC*4);     // MC bf16
    char* p3 = p2 + MC*2 + 2*MC*4 + MC*2;
    unsigned short* Wqkv_t = (unsigned short*)p3;                        // [1152][384]
    unsigned short* Wo_t   = Wqkv_t + (size_t)3*C_DIM*C_DIM;             // [384][384]
    unsigned short* W1_t   = Wo_t   + (size_t)C_DIM*C_DIM;               // [1536][384]
    unsigned short* W2_t   = W1_t   + (size_t)FF_DIM*C_DIM;              // [384][1536]

    dim3 b256(256), b328(32, 8);

    // ---- all weight transposes + x->bf16 in ONE launch ----
    prep_all<<<dim3(1728 + 3072), b328, 0, stream>>>(
        Wq, Wk, Wv, Wo, W1, W2, x, Wqkv_t, Wo_t, W1_t, W2_t, xb);

    // ---- qkv = xb @ Wqkv (Q pre-scaled; K written straight to ktc) ----
    gemm_lds<1, 0, 0, 1, 1><<<dim3(3*C_DIM/128, M/128), b256, 0, stream>>>(
        xb, Wqkv_t, nullptr, qkv, ktc, M, 3*C_DIM, C_DIM);

    // ---- V transpose ----
    vtrans_kernel<<<dim3(TSEQ/32, HD/32, BATCH*HEADS), b328, 0, stream>>>(qkv, vt);

    // ---- attention: 192 x 8-wave shared-KV blocks, direct store ----
    attn8_kernel<<<dim3(192), dim3(512), 0, stream>>>(qkv, ktc, vt, att);

    // ---- y = att @ Wo + bo  (BM=64, double-buffered) ----
    gemm_lds64<0, 1, 0><<<dim3(C_DIM/128, M/64), b256, 0, stream>>>(
        att, Wo_t, bo, y, M, C_DIM, C_DIM);

    // ---- x1b = LN(x + y)  (bf16 only) ----
    ln_residual_kernel<0, 0, 1><<<dim3(M/4), b256, 0, stream>>>(
        x, y, g1, be1, nullptr, x1b, M);

    // ---- h1 = relu(x1b @ W1 + b1) ----
    gemm_lds<1, 1, 1, 0, 0><<<dim3(FF_DIM/128, M/128), b256, 0, stream>>>(
        x1b, W1_t, b1, h1, nullptr, M, FF_DIM, C_DIM);

    // ---- y = h1 @ W2 + b2  (BM=64, double-buffered, K=1536) ----
    gemm_lds64<0, 1, 0><<<dim3(C_DIM/128, M/64), b256, 0, stream>>>(
        h1, W2_t, b2, y, M, C_DIM, FF_DIM);

    // ---- out = LN(x1b + y) ----
    ln_residual_kernel<1, 1, 0><<<dim3(M/4), b256, 0, stream>>>(
        x1b, y, g2, be2, out, nullptr, M);
}

// Round 20
// 192.072 us; speedup vs baseline: 1.1126x; 1.1126x over previous
//
#include <hip/hip_runtime.h>

#define C_DIM  384
#define HEADS  6
#define HD     64
#define FF_DIM 1536
#define LN_EPS 1e-3f
#define TSEQ   2048
#define BATCH  4
#define LOG2E  1.4426950408889634f
#define QK_SCALE 0.18033688011112042f   // 0.125 * log2(e), folded into Q

typedef __attribute__((ext_vector_type(2))) float          f32x2;
typedef __attribute__((ext_vector_type(4))) float          f32x4;
typedef __attribute__((ext_vector_type(4))) float          float4_t;
typedef __attribute__((ext_vector_type(8))) short          bfrag;     // 8 bf16
typedef __attribute__((ext_vector_type(4))) unsigned short ushort4_t;
typedef __attribute__((ext_vector_type(8))) unsigned short ushort8_t;

__device__ inline unsigned short f2bf(float f) {
    unsigned int u = __builtin_bit_cast(unsigned int, f);
    u += 0x7fff + ((u >> 16) & 1);          // RNE
    return (unsigned short)(u >> 16);
}
// truncating convert — P matrix only (values in [0,1], re-normalized)
__device__ inline unsigned short f2bf_t(float f) {
    return (unsigned short)(__builtin_bit_cast(unsigned int, f) >> 16);
}
__device__ inline float bf2f(unsigned short u) {
    return __builtin_bit_cast(float, (unsigned int)u << 16);
}

// async global->LDS, 16 B per lane. LDS dest is wave-uniform base + lane*16.
__device__ inline void gload_lds16(const void* g, void* l) {
    __builtin_amdgcn_global_load_lds(
        (const __attribute__((address_space(1))) unsigned int*)g,
        (__attribute__((address_space(3))) unsigned int*)l,
        16, 0, 0);
}

// chunked XCD swizzle: HW maps flat blockIdx round-robin (bid&7 = XCD, r10).
// Remap so each XCD owns a CONTIGUOUS logical range (A-panel L2 locality).
// Requires nwg % 8 == 0 (true for all GEMM grids here).
__device__ inline int xcd_chunk(int flat, int nwg) {
    return (flat >> 3) + (flat & 7) * (nwg >> 3);
}

// ---------------------------------------------------------------------------
// Fused: all weight transposes (W[K][N] f32 -> Wt[N][K] bf16) + x -> bf16.
// Blocks 0..575: four 384x384; 576..1151: W1; 1152..1727: W2;
// 1728..4799: cvt x (3072 blocks x 256 float4 = exact). block (32,8).
// ---------------------------------------------------------------------------
__global__ __launch_bounds__(256)
void prep_all(const float* __restrict__ Wq, const float* __restrict__ Wk,
              const float* __restrict__ Wv, const float* __restrict__ Wo,
              const float* __restrict__ W1, const float* __restrict__ W2,
              const float* __restrict__ x,
              unsigned short* __restrict__ Dqkv, unsigned short* __restrict__ Do_,
              unsigned short* __restrict__ D1, unsigned short* __restrict__ D2,
              unsigned short* __restrict__ xb)
{
    __shared__ float tile[32][33];
    const int bidx = blockIdx.x;
    const int tx = threadIdx.x, ty = threadIdx.y;
    if (bidx >= 1728) {
        const int i = (bidx - 1728) * 256 + ty * 32 + tx;
        float4_t v = ((const float4_t*)x)[i];
        ushort4_t o = { f2bf(v.x), f2bf(v.y), f2bf(v.z), f2bf(v.w) };
        ((ushort4_t*)xb)[i] = o;
        return;
    }
    const float* W; unsigned short* D;
    int K, N, nx, ny;
    if (bidx < 576) {
        const int z = bidx / 144, r = bidx % 144;
        W = z == 0 ? Wq : (z == 1 ? Wk : (z == 2 ? Wv : Wo));
        D = z == 3 ? Do_ : Dqkv + (size_t)z * C_DIM * C_DIM;
        K = N = C_DIM; nx = r % 12; ny = r / 12;
    } else if (bidx < 1152) {
        const int r = bidx - 576;
        W = W1; D = D1; K = C_DIM; N = FF_DIM; nx = r % 48; ny = r / 48;
    } else {
        const int r = bidx - 1152;
        W = W2; D = D2; K = FF_DIM; N = C_DIM; nx = r % 12; ny = r / 12;
    }
    const int n0 = nx * 32, k0 = ny * 32;
    #pragma unroll
    for (int i = 0; i < 32; i += 8)
        tile[ty + i][tx] = W[(size_t)(k0 + ty + i) * N + n0 + tx];
    __syncthreads();
    #pragma unroll
    for (int i = 0; i < 32; i += 8)
        D[(size_t)(n0 + ty + i) * K + k0 + tx] = f2bf(tile[tx][ty + i]);
}

// ---------------------------------------------------------------------------
// V transpose only: qkv v-cols -> vt[bh][d][t] bf16.
// ---------------------------------------------------------------------------
__global__ __launch_bounds__(256)
void vtrans_kernel(const unsigned short* __restrict__ qkv,
                   unsigned short* __restrict__ vt)
{
    __shared__ unsigned short tile[32][34];
    const int tx = threadIdx.x, ty = threadIdx.y;
    const int bh = blockIdx.z, b = bh / HEADS, h = bh % HEADS;
    const int t0 = blockIdx.x * 32, d0 = blockIdx.y * 32;
    #pragma unroll
    for (int i = 0; i < 32; i += 8)
        tile[ty + i][tx] = qkv[(size_t)(b * TSEQ + t0 + ty + i) * 1152 + 2 * C_DIM + h * HD + d0 + tx];
    __syncthreads();
    #pragma unroll
    for (int i = 0; i < 32; i += 8)
        vt[((size_t)bh * HD + d0 + ty + i) * TSEQ + t0 + tx] = tile[tx][ty + i];
}

// ---------------------------------------------------------------------------
// LDS-staged bf16 MFMA GEMM, BM=128 x BN=128 (m97 structure), fragment-major
// gload_lds staging. QSCALE: scale output cols < C_DIM by QK_SCALE.
// KSPLIT: cols [C_DIM, 2*C_DIM) written to ktc[bh][t][d] (fused K-repack).
// Chunked XCD swizzle on the flat block id (T1).
// ---------------------------------------------------------------------------
template<int OBF16, int BIAS, int RELU, int QSCALE, int KSPLIT>
__global__ __launch_bounds__(256)
void gemm_lds(const unsigned short* __restrict__ A, const unsigned short* __restrict__ Bt,
              const float* __restrict__ bias, void* __restrict__ Cv,
              unsigned short* __restrict__ ktc,
              int M, int N, int K)
{
    __shared__ __align__(16) unsigned short As[16 * 512];   // 16 frags x 1KB
    __shared__ __align__(16) unsigned short Bs[16 * 512];

    const int t = threadIdx.x, lane = t & 63, w = t >> 6;
    const int ln16 = lane & 15, hi16 = lane >> 4;
    const int wr = w >> 1, wc = w & 1;
    const int nwg = gridDim.x * gridDim.y;
    const int L = xcd_chunk(blockIdx.y * gridDim.x + blockIdx.x, nwg);
    const int row0 = (L / gridDim.x) * 128, col0 = (L % gridDim.x) * 128;

    f32x4 acc[4][4] = {};

    for (int k0 = 0; k0 < K; k0 += 64) {
        #pragma unroll
        for (int i = 0; i < 4; ++i) {
            const int f  = w * 4 + i;
            const int ks = f >> 3, rf = f & 7;
            const int row = rf * 16 + ln16;
            const int kc  = k0 + ks * 32 + hi16 * 8;
            gload_lds16(&A [(size_t)(row0 + row) * K + kc], &As[f * 512]);
            gload_lds16(&Bt[(size_t)(col0 + row) * K + kc], &Bs[f * 512]);
        }
        __syncthreads();
        #pragma unroll
        for (int ks = 0; ks < 2; ++ks) {
            bfrag a[4], b[4];
            #pragma unroll
            for (int i = 0; i < 4; ++i)
                a[i] = *(const bfrag*)&As[(ks * 8 + wr * 4 + i) * 512 + lane * 8];
            #pragma unroll
            for (int j = 0; j < 4; ++j)
                b[j] = *(const bfrag*)&Bs[(ks * 8 + wc * 4 + j) * 512 + lane * 8];
            #pragma unroll
            for (int i = 0; i < 4; ++i)
                #pragma unroll
                for (int j = 0; j < 4; ++j)
                    acc[i][j] = __builtin_amdgcn_mfma_f32_16x16x32_bf16(a[i], b[j], acc[i][j], 0, 0, 0);
        }
        __syncthreads();
    }

    #pragma unroll
    for (int j = 0; j < 4; ++j) {
        const int cbase = col0 + wc * 64 + j * 16;      // 16-aligned, head-uniform
        const int col = cbase + ln16;
        const float bv = BIAS ? bias[col] : 0.0f;
        const float sc = (QSCALE && col < C_DIM) ? QK_SCALE : 1.0f;
        const bool kdest = KSPLIT && (cbase >= C_DIM) && (cbase < 2 * C_DIM);
        #pragma unroll
        for (int i = 0; i < 4; ++i) {
            #pragma unroll
            for (int e = 0; e < 4; ++e) {
                const int row = row0 + wr * 64 + i * 16 + hi16 * 4 + e;
                float v = acc[i][j][e] + bv;
                if (RELU) v = fmaxf(v, 0.0f);
                if (QSCALE) v *= sc;
                if (kdest) {
                    const int b  = row >> 11, tt = row & 2047;
                    const int hd = col - C_DIM;                 // h*64 + d
                    const int bh = b * HEADS + (hd >> 6);
                    ktc[((size_t)bh * TSEQ + tt) * HD + (hd & 63)] = f2bf(v);
                } else if (OBF16) {
                    ((unsigned short*)Cv)[(size_t)row * N + col] = f2bf(v);
                } else {
                    ((float*)Cv)[(size_t)row * N + col] = v;
                }
            }
        }
    }
}

// ---------------------------------------------------------------------------
// LDS-staged bf16 MFMA GEMM, BM=64 x BN=128 — for small-N GEMMs (N=384).
// DOUBLE-BUFFERED LDS (T3-minimum 2-phase). Chunked XCD swizzle (T1).
// ---------------------------------------------------------------------------
template<int OBF16, int BIAS, int RELU>
__global__ __launch_bounds__(256)
void gemm_lds64(const unsigned short* __restrict__ A, const unsigned short* __restrict__ Bt,
                const float* __restrict__ bias, void* __restrict__ Cv,
                int M, int N, int K)
{
    __shared__ __align__(16) unsigned short As[2][8 * 512];    // 2 x 8 frags
    __shared__ __align__(16) unsigned short Bs[2][16 * 512];   // 2 x 16 frags

    const int t = threadIdx.x, lane = t & 63, w = t >> 6;
    const int ln16 = lane & 15, hi16 = lane >> 4;
    const int wr = w >> 1, wc = w & 1;
    const int nwg = gridDim.x * gridDim.y;
    const int L = xcd_chunk(blockIdx.y * gridDim.x + blockIdx.x, nwg);
    const int row0 = (L / gridDim.x) * 64, col0 = (L % gridDim.x) * 128;

    f32x4 acc[2][4] = {};

    auto stage = [&](int bf, int k0) {
        #pragma unroll
        for (int i = 0; i < 2; ++i) {
            const int f  = w * 2 + i;
            const int ks = f >> 2, rf = f & 3;
            gload_lds16(&A[(size_t)(row0 + rf * 16 + ln16) * K + k0 + ks * 32 + hi16 * 8],
                        &As[bf][f * 512]);
        }
        #pragma unroll
        for (int i = 0; i < 4; ++i) {
            const int f  = w * 4 + i;
            const int ks = f >> 3, cf = f & 7;
            gload_lds16(&Bt[(size_t)(col0 + cf * 16 + ln16) * K + k0 + ks * 32 + hi16 * 8],
                        &Bs[bf][f * 512]);
        }
    };

    int buf = 0;
    stage(0, 0);
    __syncthreads();                       // buf0 staged

    for (int k0 = 0; k0 < K; k0 += 64) {
        if (k0 + 64 < K) stage(buf ^ 1, k0 + 64);   // async, in flight over compute
        #pragma unroll
        for (int ks = 0; ks < 2; ++ks) {
            bfrag a[2], b[4];
            #pragma unroll
            for (int i = 0; i < 2; ++i)
                a[i] = *(const bfrag*)&As[buf][(ks * 4 + wr * 2 + i) * 512 + lane * 8];
            #pragma unroll
            for (int j = 0; j < 4; ++j)
                b[j] = *(const bfrag*)&Bs[buf][(ks * 8 + wc * 4 + j) * 512 + lane * 8];
            #pragma unroll
            for (int i = 0; i < 2; ++i)
                #pragma unroll
                for (int j = 0; j < 4; ++j)
                    acc[i][j] = __builtin_amdgcn_mfma_f32_16x16x32_bf16(a[i], b[j], acc[i][j], 0, 0, 0);
        }
        __syncthreads();                   // drains staging vmcnt + guards reuse
        buf ^= 1;
    }

    #pragma unroll
    for (int j = 0; j < 4; ++j) {
        const int col = col0 + wc * 64 + j * 16 + ln16;
        const float bv = BIAS ? bias[col] : 0.0f;
        #pragma unroll
        for (int i = 0; i < 2; ++i) {
            #pragma unroll
            for (int e = 0; e < 4; ++e) {
                const int row = row0 + wr * 32 + i * 16 + hi16 * 4 + e;
                float v = acc[i][j][e] + bv;
                if (RELU) v = fmaxf(v, 0.0f);
                if (OBF16) ((unsigned short*)Cv)[(size_t)row * N + col] = f2bf(v);
                else       ((float*)Cv)[(size_t)row * N + col] = v;
            }
        }
    }
}

// ---------------------------------------------------------------------------
// attention helpers (s_setprio(1) around MFMA clusters — T5)
// ---------------------------------------------------------------------------
__device__ inline void qk16(const bfrag (&qf)[2][2], const bfrag (&kf)[4][2],
                            f32x4 (&sf)[2][4])
{
    __builtin_amdgcn_s_setprio(1);
    #pragma unroll
    for (int jt = 0; jt < 4; ++jt)
        #pragma unroll
        for (int ks = 0; ks < 2; ++ks) {
            sf[0][jt] = __builtin_amdgcn_mfma_f32_16x16x32_bf16(qf[0][ks], kf[jt][ks], sf[0][jt], 0, 0, 0);
            sf[1][jt] = __builtin_amdgcn_mfma_f32_16x16x32_bf16(qf[1][ks], kf[jt][ks], sf[1][jt], 0, 0, 0);
        }
    __builtin_amdgcn_s_setprio(0);
}

// softmax + PV. Mask applied on the fly.
__device__ inline void softmax_pv(f32x4 (&sf)[2][4], const bfrag (&vf)[4][2],
                                  f32x4 (&acc)[2][4],
                                  float (&mrow)[2][4], float (&lrow)[2][4],
                                  unsigned short (*Ps)[72],
                                  int tok0, int kt, bool last, int ln16, int hi16)
{
    float lmax[2][4];
    bool need = false;
    #pragma unroll
    for (int rf = 0; rf < 2; ++rf)
        #pragma unroll
        for (int e = 0; e < 4; ++e) {
            const int row = tok0 + rf * 16 + hi16 * 4 + e;
            float mx = -1e30f;
            #pragma unroll
            for (int jt = 0; jt < 4; ++jt) {
                float sv = sf[rf][jt][e];
                if (last && (kt * 64 + jt * 16 + ln16 > row)) sv = -1e30f;
                mx = fmaxf(mx, sv);
            }
            lmax[rf][e] = mx;
            need = need || (mx > mrow[rf][e] + 8.0f);
        }
    if (__any(need)) {
        #pragma unroll
        for (int rf = 0; rf < 2; ++rf)
            #pragma unroll
            for (int e = 0; e < 4; ++e) {
                float rm = lmax[rf][e];
                rm = fmaxf(rm, __shfl_xor(rm, 1));
                rm = fmaxf(rm, __shfl_xor(rm, 2));
                rm = fmaxf(rm, __shfl_xor(rm, 4));
                rm = fmaxf(rm, __shfl_xor(rm, 8));
                const float mn = fmaxf(mrow[rf][e], rm);
                const float corr = exp2f(mrow[rf][e] - mn);
                mrow[rf][e] = mn;
                lrow[rf][e] *= corr;
                #pragma unroll
                for (int dt = 0; dt < 4; ++dt) acc[rf][dt][e] *= corr;
            }
    }

    #pragma unroll
    for (int rf = 0; rf < 2; ++rf)
        #pragma unroll
        for (int jt = 0; jt < 4; ++jt)
            #pragma unroll
            for (int e = 0; e < 4; ++e) {
                const int row = tok0 + rf * 16 + hi16 * 4 + e;
                float sv = sf[rf][jt][e];
                if (last && (kt * 64 + jt * 16 + ln16 > row)) sv = -1e30f;
                const float pe = exp2f(sv - mrow[rf][e]);
                lrow[rf][e] += pe;
                Ps[rf * 16 + hi16 * 4 + e][jt * 16 + ln16] = f2bf_t(pe);
            }

    bfrag pf[2][2];
    #pragma unroll
    for (int rf = 0; rf < 2; ++rf)
        #pragma unroll
        for (int ks = 0; ks < 2; ++ks)
            pf[rf][ks] = *(const bfrag*)&Ps[rf * 16 + ln16][ks * 32 + hi16 * 8];
    __builtin_amdgcn_s_setprio(1);
    #pragma unroll
    for (int ks = 0; ks < 2; ++ks)
        #pragma unroll
        for (int rf = 0; rf < 2; ++rf)
            #pragma unroll
            for (int dt = 0; dt < 4; ++dt)
                acc[rf][dt] = __builtin_amdgcn_mfma_f32_16x16x32_bf16(pf[rf][ks], vf[dt][ks], acc[rf][dt], 0, 0, 0);
    __builtin_amdgcn_s_setprio(0);
}

// ---------------------------------------------------------------------------
// Split-K flash attention (moderate split, r15 structure — at its
// concurrency-throughput floor).
// ---------------------------------------------------------------------------
__global__ __launch_bounds__(64)
void attn_kernel(const unsigned short* __restrict__ qkv,
                 const unsigned short* __restrict__ ktc,
                 const unsigned short* __restrict__ vt,
                 unsigned short* __restrict__ att,
                 unsigned short* __restrict__ pacc,
                 float* __restrict__ pml)
{
    __shared__ __align__(16) unsigned short Ps[32][72];
    const int lane = threadIdx.x;
    const int ln16 = lane & 15, hi16 = lane >> 4;
    const int bid = blockIdx.x;            // 0..2303
    const int xcd = bid & 7;
    const int i   = bid >> 3;              // 0..287
    int bh, qw, kt0, kte, ck = 0;
    bool heavy;
    if (i < 192) {                         // heavy chunk waves, qw descending
        qw = 63 - (i / 6);                 // 63..32
        const int r = i % 6;
        bh = xcd * 3 + (r >> 1);
        ck = r & 1;
        const int NT = (qw >> 1) + 1;      // 17..32
        const int half = NT >> 1;          // 8..16
        kt0 = ck ? half : 0;
        kte = ck ? NT : half;
        heavy = true;
    } else {                               // light strips
        const int j = i - 192;             // 0..95
        qw = 31 - (j / 3);                 // 31..0
        bh = xcd * 3 + (j % 3);
        kt0 = 0;
        kte = (qw >> 1) + 1;               // <= 16
        heavy = false;
    }
    const int NTfull = (qw >> 1) + 1;
    const int b = bh / HEADS, h = bh % HEADS;
    const int tok0 = qw * 32;
    const size_t qrow0 = (size_t)b * TSEQ;

    bfrag qf[2][2];
    #pragma unroll
    for (int rf = 0; rf < 2; ++rf)
        #pragma unroll
        for (int ks = 0; ks < 2; ++ks)
            qf[rf][ks] = *(const bfrag*)&qkv[(qrow0 + tok0 + rf * 16 + ln16) * 1152 + h * HD + ks * 32 + hi16 * 8];

    f32x4 acc[2][4] = {};
    float mrow[2][4], lrow[2][4];
    #pragma unroll
    for (int rf = 0; rf < 2; ++rf)
        #pragma unroll
        for (int e = 0; e < 4; ++e) { mrow[rf][e] = -1e30f; lrow[rf][e] = 0.0f; }

    const unsigned short* Kb = ktc + (size_t)bh * TSEQ * HD;
    const unsigned short* Vb = vt  + (size_t)bh * HD * TSEQ;

    bfrag kf[4][2];
    #pragma unroll
    for (int jt = 0; jt < 4; ++jt)
        #pragma unroll
        for (int ks = 0; ks < 2; ++ks)
            kf[jt][ks] = *(const bfrag*)&Kb[(size_t)(kt0 * 64 + jt * 16 + ln16) * HD + ks * 32 + hi16 * 8];

    for (int kt = kt0; kt < kte; ++kt) {
        bfrag vf[4][2];
        #pragma unroll
        for (int dt = 0; dt < 4; ++dt)
            #pragma unroll
            for (int ks = 0; ks < 2; ++ks)
                vf[dt][ks] = *(const bfrag*)&Vb[(size_t)(dt * 16 + ln16) * TSEQ + kt * 64 + ks * 32 + hi16 * 8];

        f32x4 sf[2][4] = {};
        qk16(qf, kf, sf);

        if (kt + 1 < kte) {
            #pragma unroll
            for (int jt = 0; jt < 4; ++jt)
                #pragma unroll
                for (int ks = 0; ks < 2; ++ks)
                    kf[jt][ks] = *(const bfrag*)&Kb[(size_t)((kt + 1) * 64 + jt * 16 + ln16) * HD + ks * 32 + hi16 * 8];
        }

        softmax_pv(sf, vf, acc, mrow, lrow, Ps, tok0, kt, kt == NTfull - 1, ln16, hi16);
    }

    float lsum[2][4];
    #pragma unroll
    for (int rf = 0; rf < 2; ++rf)
        #pragma unroll
        for (int e = 0; e < 4; ++e) {
            float l = lrow[rf][e];
            l += __shfl_xor(l, 1);
            l += __shfl_xor(l, 2);
            l += __shfl_xor(l, 4);
            l += __shfl_xor(l, 8);
            lsum[rf][e] = l;
        }

    if (!heavy) {
        #pragma unroll
        for (int rf = 0; rf < 2; ++rf)
            #pragma unroll
            for (int e = 0; e < 4; ++e) {
                const float inv = 1.0f / lsum[rf][e];
                const size_t row = qrow0 + tok0 + rf * 16 + hi16 * 4 + e;
                #pragma unroll
                for (int dt = 0; dt < 4; ++dt)
                    att[row * C_DIM + h * HD + dt * 16 + ln16] = f2bf(acc[rf][dt][e] * inv);
            }
    } else {
        const int sidx = bh * 32 + (qw - 32);     // 0..767
        const size_t pb = (size_t)sidx * 2 + ck;
        #pragma unroll
        for (int rf = 0; rf < 2; ++rf)
            #pragma unroll
            for (int dt = 0; dt < 4; ++dt)
                #pragma unroll
                for (int e = 0; e < 4; ++e) {
                    const int row = rf * 16 + hi16 * 4 + e;
                    pacc[(pb * 32 + row) * 64 + dt * 16 + ln16] = f2bf(acc[rf][dt][e]);
                }
        if (ln16 == 0) {
            #pragma unroll
            for (int rf = 0; rf < 2; ++rf)
                #pragma unroll
                for (int e = 0; e < 4; ++e) {
                    const int row = rf * 16 + hi16 * 4 + e;
                    pml[pb * 64 + row * 2 + 0] = mrow[rf][e];
                    pml[pb * 64 + row * 2 + 1] = lsum[rf][e];
                }
        }
    }
}

// ---------------------------------------------------------------------------
// Combine the 2 chunks of each heavy strip. 768 blocks x 256 thr.
// ---------------------------------------------------------------------------
__global__ __launch_bounds__(256)
void attn_combine(const unsigned short* __restrict__ pacc,
                  const float* __restrict__ pml,
                  unsigned short* __restrict__ att)
{
    const int sidx = blockIdx.x;           // 0..767
    const int bh = sidx >> 5;
    const int qw = 32 + (sidx & 31);
    const int b = bh / HEADS, h = bh % HEADS;
    const int tid = threadIdx.x;
    const int row = tid >> 3;              // 0..31
    const int d0  = (tid & 7) * 8;

    const float m0 = pml[((size_t)sidx * 2 + 0) * 64 + row * 2 + 0];
    const float l0 = pml[((size_t)sidx * 2 + 0) * 64 + row * 2 + 1];
    const float m1 = pml[((size_t)sidx * 2 + 1) * 64 + row * 2 + 0];
    const float l1 = pml[((size_t)sidx * 2 + 1) * 64 + row * 2 + 1];
    const float M  = fmaxf(m0, m1);
    const float w0 = exp2f(m0 - M), w1 = exp2f(m1 - M);
    const float invL = 1.0f / (l0 * w0 + l1 * w1);

    ushort8_t a0 = *(const ushort8_t*)&pacc[(((size_t)sidx * 2 + 0) * 32 + row) * 64 + d0];
    ushort8_t a1 = *(const ushort8_t*)&pacc[(((size_t)sidx * 2 + 1) * 32 + row) * 64 + d0];
    ushort8_t rv;
    #pragma unroll
    for (int k = 0; k < 8; ++k) {
        const float v0 = bf2f(a0[k]);
        const float v1 = bf2f(a1[k]);
        rv[k] = f2bf((v0 * w0 + v1 * w1) * invL);
    }
    const size_t grow = (size_t)b * TSEQ + qw * 32 + row;
    *(ushort8_t*)&att[grow * C_DIM + h * HD + d0] = rv;
}

// ---------------------------------------------------------------------------
// Fused residual add + LayerNorm, vectorized (f32x2 / packed-u32 paths).
// ABF16: residual input A is bf16. WF32: write f32 out. WBF: write bf16 out.
// ---------------------------------------------------------------------------
template<int ABF16, int WF32, int WBF>
__global__ __launch_bounds__(256)
void ln_residual_kernel(const void* __restrict__ Av, const float* __restrict__ R,
                        const float* __restrict__ gamma, const float* __restrict__ beta,
                        float* __restrict__ out, unsigned short* __restrict__ outb, int Mrows)
{
    const int lane = threadIdx.x & 63;
    const int wv   = threadIdx.x >> 6;
    const int row  = blockIdx.x * 4 + wv;
    if (row >= Mrows) return;
    const size_t off = (size_t)row * C_DIM;

    float v[6];
    float sum = 0.0f;
    #pragma unroll
    for (int j = 0; j < 3; ++j) {
        const int c = lane * 2 + 128 * j;
        float a0, a1;
        if (ABF16) {
            const unsigned int u = *(const unsigned int*)&((const unsigned short*)Av)[off + c];
            a0 = bf2f((unsigned short)(u & 0xffff));
            a1 = bf2f((unsigned short)(u >> 16));
        } else {
            f32x2 a = *(const f32x2*)&((const float*)Av)[off + c];
            a0 = a.x; a1 = a.y;
        }
        f32x2 r = *(const f32x2*)&R[off + c];
        v[2 * j]     = a0 + r.x;
        v[2 * j + 1] = a1 + r.y;
        sum += v[2 * j] + v[2 * j + 1];
    }
    #pragma unroll
    for (int o = 1; o < 64; o <<= 1) sum += __shfl_xor(sum, o);
    const float mu = sum * (1.0f / C_DIM);

    float sq = 0.0f;
    #pragma unroll
    for (int j = 0; j < 6; ++j) { const float d = v[j] - mu; sq = fmaf(d, d, sq); }
    #pragma unroll
    for (int o = 1; o < 64; o <<= 1) sq += __shfl_xor(sq, o);
    const float rstd = rsqrtf(sq * (1.0f / C_DIM) + LN_EPS);

    #pragma unroll
    for (int j = 0; j < 3; ++j) {
        const int c = lane * 2 + 128 * j;
        f32x2 g  = *(const f32x2*)&gamma[c];
        f32x2 be = *(const f32x2*)&beta[c];
        const float r0 = (v[2 * j]     - mu) * rstd * g.x + be.x;
        const float r1 = (v[2 * j + 1] - mu) * rstd * g.y + be.y;
        if (WF32) { f32x2 o = { r0, r1 }; *(f32x2*)&out[off + c] = o; }
        if (WBF) {
            const unsigned int o = (unsigned int)f2bf(r0) | ((unsigned int)f2bf(r1) << 16);
            *(unsigned int*)&outb[off + c] = o;
        }
    }
}

// ---------------------------------------------------------------------------
extern "C" void kernel_launch(void* const* d_in, const int* in_sizes, int n_in,
                              void* d_out, int out_size, void* d_ws, size_t ws_size,
                              hipStream_t stream)
{
    const float* x   = (const float*)d_in[0];
    const float* Wq  = (const float*)d_in[1];
    const float* Wk  = (const float*)d_in[2];
    const float* Wv  = (const float*)d_in[3];
    const float* Wo  = (const float*)d_in[4];
    const float* bo  = (const float*)d_in[5];
    const float* W1  = (const float*)d_in[6];
    const float* b1  = (const float*)d_in[7];
    const float* W2  = (const float*)d_in[8];
    const float* b2  = (const float*)d_in[9];
    const float* g1  = (const float*)d_in[10];
    const float* be1 = (const float*)d_in[11];
    const float* g2  = (const float*)d_in[12];
    const float* be2 = (const float*)d_in[13];
    float* out = (float*)d_out;

    const int M = BATCH * TSEQ;                  // 8192
    const size_t MC = (size_t)M * C_DIM;

    // ---- workspace layout (bytes) ----
    char* ws = (char*)d_ws;
    unsigned short* qkv = (unsigned short*)ws;                       // M*1152*2 = 18.87 MB
    unsigned short* vt  = (unsigned short*)(ws + (size_t)M*1152*2);  // 6.29 MB
    unsigned short* att = (unsigned short*)(ws + (size_t)M*1152*2 + (size_t)BATCH*HEADS*HD*TSEQ*2); // 6.29 MB
    unsigned short* h1  = (unsigned short*)ws;                       // M*1536*2, aliases qkv+vt
    char* p2 = ws + (size_t)M*1152*2 + (size_t)BATCH*HEADS*HD*TSEQ*2 + MC*2;   // 31.46 MB mark
    unsigned short* xb  = (unsigned short*)p2;                       // MC bf16 (QKV gemm input)
    float* y   = (float*)(p2 + MC*2);                                // MC f32
    unsigned short* ktc = (unsigned short*)(p2 + MC*2 + MC*4);       // 6.29 MB
    unsigned short* x1b = (unsigned short*)(p2 + MC*2 + 2*MC*4);     // MC bf16
    char* p3 = p2 + MC*2 + 2*MC*4 + MC*2;
    unsigned short* Wqkv_t = (unsigned short*)p3;                        // [1152][384]
    unsigned short* Wo_t   = Wqkv_t + (size_t)3*C_DIM*C_DIM;             // [384][384]
    unsigned short* W1_t   = Wo_t   + (size_t)C_DIM*C_DIM;               // [1536][384]
    unsigned short* W2_t   = W1_t   + (size_t)FF_DIM*C_DIM;              // [384][1536]

    // split-K partials in y region (dead during attn):
    unsigned short* pacc = (unsigned short*)(p2 + MC*2);
    float* pml = (float*)(p2 + MC*2 + (size_t)1536*32*64*2);

    dim3 b256(256), b328(32, 8);

    // ---- all weight transposes + x->bf16 in ONE launch ----
    prep_all<<<dim3(1728 + 3072), b328, 0, stream>>>(
        Wq, Wk, Wv, Wo, W1, W2, x, Wqkv_t, Wo_t, W1_t, W2_t, xb);

    // ---- qkv = xb @ Wqkv (Q pre-scaled; K written straight to ktc) ----
    gemm_lds<1, 0, 0, 1, 1><<<dim3(3*C_DIM/128, M/128), b256, 0, stream>>>(
        xb, Wqkv_t, nullptr, qkv, ktc, M, 3*C_DIM, C_DIM);

    // ---- V transpose ----
    vtrans_kernel<<<dim3(TSEQ/32, HD/32, BATCH*HEADS), b328, 0, stream>>>(qkv, vt);

    // ---- attention: 2304 waves (heavy strips split in 2), then combine ----
    attn_kernel<<<dim3(2304), dim3(64), 0, stream>>>(qkv, ktc, vt, att, pacc, pml);
    attn_combine<<<dim3(768), b256, 0, stream>>>(pacc, pml, att);

    // ---- y = att @ Wo + bo  (BM=64, double-buffered) ----
    gemm_lds64<0, 1, 0><<<dim3(C_DIM/128, M/64), b256, 0, stream>>>(
        att, Wo_t, bo, y, M, C_DIM, C_DIM);

    // ---- x1b = LN(x + y)  (bf16 only) ----
    ln_residual_kernel<0, 0, 1><<<dim3(M/4), b256, 0, stream>>>(
        x, y, g1, be1, nullptr, x1b, M);

    // ---- h1 = relu(x1b @ W1 + b1) ----
    gemm_lds<1, 1, 1, 0, 0><<<dim3(FF_DIM/128, M/128), b256, 0, stream>>>(
        x1b, W1_t, b1, h1, nullptr, M, FF_DIM, C_DIM);

    // ---- y = h1 @ W2 + b2  (BM=64, double-buffered, K=1536) ----
    gemm_lds64<0, 1, 0><<<dim3(C_DIM/128, M/64), b256, 0, stream>>>(
        h1, W2_t, b2, y, M, C_DIM, FF_DIM);

    // ---- out = LN(x1b + y) ----
    ln_residual_kernel<1, 1, 0><<<dim3(M/4), b256, 0, stream>>>(
        x1b, y, g2, be2, out, nullptr, M);
}